// Round 12
// baseline (662.058 us; speedup 1.0000x reference)
//
#include <hip/hip_runtime.h>
#include <stdint.h>

// ---------------- problem constants (fixed by setup_inputs) ----------------
#define R_    4
#define T_    2048
#define TOPK_ 2
#define MT_   (T_ * TOPK_)   // 4096
#define Kp_   1024
#define E_    8
#define H_    4096

// ---------------- tiling ----------------
#define BM 128
#define BN 128
#define BK 64
#define NKL (Kp_ / BK)          // 16 K-steps per block (r handled by blockIdx.y)
#define MAXT 40                 // >= sum ceil(cnt_e/128)

// ws layout (int32 words)
#define WS_TE   16
#define WS_TRS  80
#define WS_TNR  144
#define WS_RIDX 256

typedef _Float16 f16x8 __attribute__((ext_vector_type(8)));
typedef __fp16   h16x2 __attribute__((ext_vector_type(2)));   // cvt_pkrtz ret type
typedef float    f32x4 __attribute__((ext_vector_type(4)));
typedef float    f32x2 __attribute__((ext_vector_type(2)));

// ---------------------------------------------------------------------------
// Kernel A: bin slots by expert in ws (placement-invariant row order)
// ---------------------------------------------------------------------------
__global__ void moe_prep(const int* __restrict__ ids, int* __restrict__ ws) {
  __shared__ int cnt[E_], off[E_], cur[E_];
  const int tid = threadIdx.x;
  if (tid < E_) { cnt[tid] = 0; cur[tid] = 0; }
  __syncthreads();
  for (int m = tid; m < MT_; m += 256) atomicAdd(&cnt[ids[m]], 1);
  __syncthreads();
  if (tid == 0) {
    int o = 0, nt = 0;
    for (int e = 0; e < E_; ++e) {
      off[e] = o;
      int c = cnt[e];
      for (int t = 0; t < (c + BM - 1) / BM; ++t) {
        ws[WS_TE + nt]  = e;
        ws[WS_TRS + nt] = o + t * BM;
        int rem = c - t * BM;
        ws[WS_TNR + nt] = rem < BM ? rem : BM;
        ++nt;
      }
      o += c;
    }
    for (; nt < MAXT; ++nt) ws[WS_TNR + nt] = 0;   // mark unused tiles
  }
  __syncthreads();
  for (int m = tid; m < MT_; m += 256) {
    int e = ids[m];
    int p = off[e] + atomicAdd(&cur[e], 1);
    ws[WS_RIDX + p] = m;
  }
}

// ---------------------------------------------------------------------------
// Kernel B: grouped GEMM 128x128xBK64, r-split over blockIdx.y,
// register-prefetch pipeline: load tile kk+1 while MFMAing tile kk.
//  A LDS [128 m][64 k] f16 (XOR swizzle), B LDS [128 h][64 k] f16 (same).
//  fp32 -> f16 via v_cvt_pkrtz (exact: inputs are fp16-valued fp32).
//  Epilogue: acc*tw[m] atomicAdd into out[t][h] (<=8 writers incl. r-split).
// ---------------------------------------------------------------------------
__global__ __launch_bounds__(256) void moe_gemm(
    const float* __restrict__ x, const float* __restrict__ w,
    const float* __restrict__ tw, const int* __restrict__ ws,
    float* __restrict__ out)
{
  __shared__ __align__(16) char Alds[16384];
  __shared__ __align__(16) char Blds[16384];

  const int bt = blockIdx.x;                  // m-tile (fastest: w-slab reuse)
  const int nr = ws[WS_TNR + bt];
  if (nr == 0) return;
  const int e  = ws[WS_TE + bt];
  const int rs = ws[WS_TRS + bt];
  const int r  = blockIdx.y;                  // K-shard
  const int h0 = blockIdx.z * BN;
  const int* __restrict__ ridx = ws + WS_RIDX;

  const int tid = threadIdx.x;
  const int wv  = tid >> 6;
  const int ln  = tid & 63;
  const int g   = ln >> 4;
  const int c16 = ln & 15;
  const int wr = wv >> 1, wc = wv & 1;

  // ---- A staging map: chunk i covers f16-tile bytes q=(tid+i*256)*16 ----
  size_t   asrc[4];   // fp32 element offset within x[r] slab (K-invariant)
  uint32_t awr[4];    // swizzled LDS write byte
#pragma unroll
  for (int i = 0; i < 4; ++i) {
    int q   = (tid + i * 256) * 16;
    int row = q >> 7;
    int el0 = (q & 127) >> 1;
    int rcl = row < nr ? row : nr - 1;
    int slot = ridx[rs + rcl];
    asrc[i] = (size_t)slot * Kp_ + el0;
    awr[i]  = row * 128 + ((q & 127) ^ ((row & 7) << 4));
  }

  // ---- B staging map: h-pair 2p,2p+1 x k-sixteenth kh ----
  const int p  = tid & 63;
  const int kh = tid >> 6;
  const int hr0 = 2 * p, hr1 = 2 * p + 1;
  uint32_t bw[4];
#pragma unroll
  for (int q = 0; q < 2; ++q) {
    bw[q]     = hr0 * 128 + ((kh * 32 + q * 16) ^ ((hr0 & 7) << 4));
    bw[2 + q] = hr1 * 128 + ((kh * 32 + q * 16) ^ ((hr1 & 7) << 4));
  }

  // ---- fragment read offsets ----
  uint32_t aoff[4][2], boff[4][2];
#pragma unroll
  for (int mi = 0; mi < 4; ++mi) {
    int row = wr * 64 + mi * 16 + c16;
#pragma unroll
    for (int ks = 0; ks < 2; ++ks)
      aoff[mi][ks] = row * 128 + ((ks * 64 + g * 16) ^ ((row & 7) << 4));
  }
#pragma unroll
  for (int ni = 0; ni < 4; ++ni) {
    int row = wc * 64 + ni * 16 + c16;
#pragma unroll
    for (int ks = 0; ks < 2; ++ks)
      boff[ni][ks] = row * 128 + ((ks * 64 + g * 16) ^ ((row & 7) << 4));
  }

  f32x4 acc[4][4];
#pragma unroll
  for (int mi = 0; mi < 4; ++mi)
#pragma unroll
    for (int ni = 0; ni < 4; ++ni)
      acc[mi][ni] = f32x4{0.f, 0.f, 0.f, 0.f};

  const float* xbase = x + (size_t)r * MT_ * Kp_;
  const float* wbase = w + ((size_t)(r * E_ + e) * Kp_) * (size_t)H_ + h0;

  // ---- prefetch registers (tile kk in flight) ----
  f32x4 av0[4], av1[4];
  f32x2 bv[16];

#define LOADT(KK_) do {                                                     \
    const float* xb_ = xbase + ((KK_) << 6);                                \
    _Pragma("unroll")                                                       \
    for (int i_ = 0; i_ < 4; ++i_) {                                        \
      av0[i_] = *(const f32x4*)(xb_ + asrc[i_]);                            \
      av1[i_] = *(const f32x4*)(xb_ + asrc[i_] + 4);                        \
    }                                                                       \
    const float* wb_ = wbase + (size_t)((KK_) << 6) * H_;                   \
    _Pragma("unroll")                                                       \
    for (int i_ = 0; i_ < 16; ++i_)                                         \
      bv[i_] = *(const f32x2*)(wb_ + (size_t)(kh * 16 + i_) * H_ + 2 * p);  \
  } while (0)

  LOADT(0);

  for (int kk = 0; kk < NKL; ++kk) {
    __syncthreads();                          // tile kk-1 consumers done
    // cvt (exact pkrtz) + swizzled LDS write of tile kk
#pragma unroll
    for (int i = 0; i < 4; ++i) {
      union { f16x8 v; h16x2 h[4]; } u;
      u.h[0] = __builtin_amdgcn_cvt_pkrtz(av0[i][0], av0[i][1]);
      u.h[1] = __builtin_amdgcn_cvt_pkrtz(av0[i][2], av0[i][3]);
      u.h[2] = __builtin_amdgcn_cvt_pkrtz(av1[i][0], av1[i][1]);
      u.h[3] = __builtin_amdgcn_cvt_pkrtz(av1[i][2], av1[i][3]);
      *(f16x8*)(Alds + awr[i]) = u.v;
    }
#pragma unroll
    for (int q = 0; q < 2; ++q) {
      union { f16x8 v; h16x2 h[4]; } lo, hi;
#pragma unroll
      for (int j = 0; j < 4; ++j) {
        lo.h[j] = __builtin_amdgcn_cvt_pkrtz(bv[q * 8 + 2 * j][0], bv[q * 8 + 2 * j + 1][0]);
        hi.h[j] = __builtin_amdgcn_cvt_pkrtz(bv[q * 8 + 2 * j][1], bv[q * 8 + 2 * j + 1][1]);
      }
      *(f16x8*)(Blds + bw[q])     = lo.v;     // h row 2p,   k octet q
      *(f16x8*)(Blds + bw[2 + q]) = hi.v;     // h row 2p+1, same octet
    }
    if (kk + 1 < NKL) LOADT(kk + 1);          // issue next tile under MFMA
    __syncthreads();                          // tile kk LDS ready

#pragma unroll
    for (int ks = 0; ks < 2; ++ks) {
      f16x8 af[4], bf[4];
#pragma unroll
      for (int mi = 0; mi < 4; ++mi)
        af[mi] = *(const f16x8*)(Alds + aoff[mi][ks]);
#pragma unroll
      for (int ni = 0; ni < 4; ++ni)
        bf[ni] = *(const f16x8*)(Blds + boff[ni][ks]);
#pragma unroll
      for (int mi = 0; mi < 4; ++mi)
#pragma unroll
        for (int ni = 0; ni < 4; ++ni)
          acc[mi][ni] = __builtin_amdgcn_mfma_f32_16x16x32_f16(
              af[mi], bf[ni], acc[mi][ni], 0, 0, 0);
    }
  }
#undef LOADT

  // ---- epilogue: tw-scale + fp32 atomic combine into out[t][h] ----
  // C/D layout (m89): col = lane&15, row = (lane>>4)*4 + reg
#pragma unroll
  for (int mi = 0; mi < 4; ++mi) {
#pragma unroll
    for (int jj = 0; jj < 4; ++jj) {
      int row = wr * 64 + mi * 16 + g * 4 + jj;
      if (row < nr) {
        int m   = ridx[rs + row];
        float twv = tw[m];
        int t = m >> 1;                        // token = slot / TOPK
        float* op = out + (size_t)t * H_ + h0 + wc * 64 + c16;
#pragma unroll
        for (int ni = 0; ni < 4; ++ni)
          atomicAdd(op + ni * 16, acc[mi][ni][jj] * twv);
      }
    }
  }
}

// ---------------------------------------------------------------------------
extern "C" void kernel_launch(void* const* d_in, const int* in_sizes, int n_in,
                              void* d_out, int out_size, void* d_ws, size_t ws_size,
                              hipStream_t stream) {
  const float* x   = (const float*)d_in[0];   // [R, MT, Kp]   fp32
  const float* w   = (const float*)d_in[1];   // [R, E, Kp, H] fp32
  const int*   ids = (const int*)d_in[2];     // [T, TOPK] int32
  const float* tw  = (const float*)d_in[3];   // [T, TOPK] fp32
  float* out = (float*)d_out;                 // [T, H] fp32
  int* ws = (int*)d_ws;

  // out accumulates via atomics; harness doesn't re-zero between replays.
  (void)hipMemsetAsync(d_out, 0, (size_t)T_ * H_ * 4, stream);
  hipLaunchKernelGGL(moe_prep, dim3(1), dim3(256), 0, stream, ids, ws);
  // grid: m-tile fastest (w-slab L2 reuse), then r, then h-tile
  hipLaunchKernelGGL(moe_gemm, dim3(MAXT, R_, H_ / BN), dim3(256), 0, stream,
                     x, w, tw, ws, out);
}

// Round 13
// 503.739 us; speedup vs baseline: 1.3143x; 1.3143x over previous
//
#include <hip/hip_runtime.h>
#include <stdint.h>

// ---------------- problem constants (fixed by setup_inputs) ----------------
#define R_    4
#define T_    2048
#define TOPK_ 2
#define MT_   (T_ * TOPK_)   // 4096
#define Kp_   1024
#define E_    8
#define H_    4096

// ---------------- tiling ----------------
#define BM 128
#define BN 128
#define BK 64
#define MAXT 40                 // >= sum ceil(cnt_e/128)

// ws layout: tables | x16 | w16T
#define WS_TE    16
#define WS_TRS   80
#define WS_TNR   144
#define WS_RIDX  256
#define WS_X16_OFF   32768
#define WS_X16_BYTES ((size_t)R_ * MT_ * Kp_ * 2)          // 33.5 MB
#define WS_W16T_OFF  (WS_X16_OFF + WS_X16_BYTES)
#define WS_W16T_BYTES ((size_t)R_ * E_ * H_ * Kp_ * 2)     // 268.4 MB
#define WS_NEEDED    (WS_W16T_OFF + WS_W16T_BYTES)

typedef _Float16 f16x8 __attribute__((ext_vector_type(8)));
typedef __fp16   h16x2 __attribute__((ext_vector_type(2)));   // cvt_pkrtz ret
typedef float    f32x4 __attribute__((ext_vector_type(4)));
typedef float    f32x2 __attribute__((ext_vector_type(2)));

__device__ __forceinline__ void gload_lds16(const void* g, void* l) {
  __builtin_amdgcn_global_load_lds(
      (const __attribute__((address_space(1))) uint8_t*)g,
      (__attribute__((address_space(3))) uint8_t*)l, 16, 0, 0);
}

// ---------------------------------------------------------------------------
// Kernel A: bin slots by expert in ws (placement-invariant row order)
// ---------------------------------------------------------------------------
__global__ void moe_prep(const int* __restrict__ ids, int* __restrict__ ws) {
  __shared__ int cnt[E_], off[E_], cur[E_];
  const int tid = threadIdx.x;
  if (tid < E_) { cnt[tid] = 0; cur[tid] = 0; }
  __syncthreads();
  for (int m = tid; m < MT_; m += 256) atomicAdd(&cnt[ids[m]], 1);
  __syncthreads();
  if (tid == 0) {
    int o = 0, nt = 0;
    for (int e = 0; e < E_; ++e) {
      off[e] = o;
      int c = cnt[e];
      for (int t = 0; t < (c + BM - 1) / BM; ++t) {
        ws[WS_TE + nt]  = e;
        ws[WS_TRS + nt] = o + t * BM;
        int rem = c - t * BM;
        ws[WS_TNR + nt] = rem < BM ? rem : BM;
        ++nt;
      }
      o += c;
    }
    for (; nt < MAXT; ++nt) ws[WS_TNR + nt] = 0;
  }
  __syncthreads();
  for (int m = tid; m < MT_; m += 256) {
    int e = ids[m];
    int p = off[e] + atomicAdd(&cur[e], 1);
    ws[WS_RIDX + p] = m;
  }
}

// ---------------------------------------------------------------------------
// Kernel B1: x fp32 -> fp16 (exact; values are fp16-representable)
// ---------------------------------------------------------------------------
__global__ void cvt_x(const float* __restrict__ x, _Float16* __restrict__ x16) {
  const size_t n = (size_t)R_ * MT_ * Kp_;
  size_t i = ((size_t)blockIdx.x * 256 + threadIdx.x) * 8;
  const size_t stride = (size_t)gridDim.x * 256 * 8;
  for (; i < n; i += stride) {
    f32x4 a = *(const f32x4*)(x + i);
    f32x4 b = *(const f32x4*)(x + i + 4);
    union { f16x8 v; h16x2 h[4]; } u;
    u.h[0] = __builtin_amdgcn_cvt_pkrtz(a[0], a[1]);
    u.h[1] = __builtin_amdgcn_cvt_pkrtz(a[2], a[3]);
    u.h[2] = __builtin_amdgcn_cvt_pkrtz(b[0], b[1]);
    u.h[3] = __builtin_amdgcn_cvt_pkrtz(b[2], b[3]);
    *(f16x8*)(x16 + i) = u.v;
  }
}

// ---------------------------------------------------------------------------
// Kernel B2: w [r][e][k][h] fp32 -> w16T [r][e][h][k] fp16, 64x64 LDS tiles
// ---------------------------------------------------------------------------
__global__ __launch_bounds__(256) void transpose_w(
    const float* __restrict__ w, _Float16* __restrict__ w16t) {
  __shared__ _Float16 tl[64][72];
  const int k0 = blockIdx.x * 64, h0 = blockIdx.y * 64;
  const float* wp = w + (size_t)blockIdx.z * Kp_ * H_;
  _Float16*    op = w16t + (size_t)blockIdx.z * H_ * Kp_;
  const int t4 = threadIdx.x & 15, kq = threadIdx.x >> 4;
#pragma unroll
  for (int i = 0; i < 4; ++i) {
    int k = k0 + kq * 4 + i;
    f32x4 v = *(const f32x4*)(wp + (size_t)k * H_ + h0 + t4 * 4);
#pragma unroll
    for (int j = 0; j < 4; ++j) tl[t4 * 4 + j][kq * 4 + i] = (_Float16)v[j];
  }
  __syncthreads();
  const int row = threadIdx.x >> 2, seg = threadIdx.x & 3;
  f16x8 o0, o1;
#pragma unroll
  for (int j = 0; j < 8; ++j) { o0[j] = tl[row][seg * 16 + j]; o1[j] = tl[row][seg * 16 + 8 + j]; }
  _Float16* dst = op + (size_t)(h0 + row) * Kp_ + k0 + seg * 16;
  *(f16x8*)dst = o0;
  *(f16x8*)(dst + 8) = o1;
}

// ---------------------------------------------------------------------------
// Kernel C: grouped GEMM on fp16 ws tensors. m97 structure: 128x128xBK64,
// full K=4096 per block, 2-barrier loop, BOTH operands staged with
// global_load_lds width-16 (linear LDS dest, inverse-XOR-swizzled source),
// fragments via swizzled ds_read_b128 (k = ks*32+g*8+j on both operands).
// ---------------------------------------------------------------------------
__global__ __launch_bounds__(256) void moe_gemm16(
    const _Float16* __restrict__ x16, const _Float16* __restrict__ w16t,
    const float* __restrict__ tw, const int* __restrict__ ws,
    float* __restrict__ out)
{
  __shared__ __align__(16) char Alds[16384];
  __shared__ __align__(16) char Blds[16384];

  const int bt = blockIdx.x;
  const int nr = ws[WS_TNR + bt];
  if (nr == 0) return;
  const int e  = ws[WS_TE + bt];
  const int rs = ws[WS_TRS + bt];
  const int h0 = blockIdx.y * BN;
  const int* __restrict__ ridx = ws + WS_RIDX;

  const int tid = threadIdx.x;
  const int wv  = tid >> 6;
  const int ln  = tid & 63;
  const int g   = ln >> 4;
  const int c16 = ln & 15;
  const int wr = wv >> 1, wc = wv & 1;

  // staging source offsets (K-invariant): chunk covers LDS byte q
  size_t asrc[4], bsrc[4];
#pragma unroll
  for (int i = 0; i < 4; ++i) {
    int q   = (tid + i * 256) * 16;
    int row = q >> 7;
    int col = (q & 127) ^ (((q >> 7) & 7) << 4);   // inverse swizzle
    int rcl = row < nr ? row : nr - 1;
    int slot = ridx[rs + rcl];
    asrc[i] = (size_t)slot * (Kp_ * 2) + col;
    bsrc[i] = (size_t)(h0 + row) * (Kp_ * 2) + col;
  }

  // fragment read offsets (proven in round 10)
  uint32_t aoff[4][2], boff[4][2];
#pragma unroll
  for (int mi = 0; mi < 4; ++mi) {
    int row = wr * 64 + mi * 16 + c16;
#pragma unroll
    for (int ks = 0; ks < 2; ++ks)
      aoff[mi][ks] = row * 128 + ((ks * 64 + g * 16) ^ ((row & 7) << 4));
  }
#pragma unroll
  for (int ni = 0; ni < 4; ++ni) {
    int row = wc * 64 + ni * 16 + c16;
#pragma unroll
    for (int ks = 0; ks < 2; ++ks)
      boff[ni][ks] = row * 128 + ((ks * 64 + g * 16) ^ ((row & 7) << 4));
  }

  f32x4 acc[4][4];
#pragma unroll
  for (int mi = 0; mi < 4; ++mi)
#pragma unroll
    for (int ni = 0; ni < 4; ++ni)
      acc[mi][ni] = f32x4{0.f, 0.f, 0.f, 0.f};

  const char* xb = (const char*)x16;
  const char* wb = (const char*)w16t + (size_t)e * H_ * Kp_ * 2;

  for (int kk = 0; kk < 4 * Kp_ / BK; ++kk) {
    const int r   = kk >> 4;
    const int kp0 = (kk & 15) << 6;
    const char* xk = xb + ((size_t)r * MT_ * Kp_ + kp0) * 2;
    const char* wk = wb + ((size_t)r * E_ * H_ * Kp_ + kp0) * 2;

    __syncthreads();                 // prev-tile consumers done
#pragma unroll
    for (int i = 0; i < 4; ++i)
      gload_lds16(xk + asrc[i], Alds + i * 4096 + wv * 1024);
#pragma unroll
    for (int i = 0; i < 4; ++i)
      gload_lds16(wk + bsrc[i], Blds + i * 4096 + wv * 1024);
    __syncthreads();                 // drains vmcnt before reads

#pragma unroll
    for (int ks = 0; ks < 2; ++ks) {
      f16x8 af[4], bf[4];
#pragma unroll
      for (int mi = 0; mi < 4; ++mi)
        af[mi] = *(const f16x8*)(Alds + aoff[mi][ks]);
#pragma unroll
      for (int ni = 0; ni < 4; ++ni)
        bf[ni] = *(const f16x8*)(Blds + boff[ni][ks]);
#pragma unroll
      for (int mi = 0; mi < 4; ++mi)
#pragma unroll
        for (int ni = 0; ni < 4; ++ni)
          acc[mi][ni] = __builtin_amdgcn_mfma_f32_16x16x32_f16(
              af[mi], bf[ni], acc[mi][ni], 0, 0, 0);
    }
  }

  // epilogue: tw-scale + atomic combine (<=2 writers per element)
#pragma unroll
  for (int mi = 0; mi < 4; ++mi) {
#pragma unroll
    for (int jj = 0; jj < 4; ++jj) {
      int row = wr * 64 + mi * 16 + g * 4 + jj;
      if (row < nr) {
        int m   = ridx[rs + row];
        float twv = tw[m];
        int t = m >> 1;
        float* op = out + (size_t)t * H_ + h0 + wc * 64 + c16;
#pragma unroll
        for (int ni = 0; ni < 4; ++ni)
          atomicAdd(op + ni * 16, acc[mi][ni][jj] * twv);
      }
    }
  }
}

// ---------------------------------------------------------------------------
// Fallback GEMM (round-12 PASS path): fp32 ingestion, reg-stage + cvt_pkrtz
// ---------------------------------------------------------------------------
__global__ __launch_bounds__(256) void moe_gemm_fb(
    const float* __restrict__ x, const float* __restrict__ w,
    const float* __restrict__ tw, const int* __restrict__ ws,
    float* __restrict__ out)
{
  __shared__ __align__(16) char Alds[16384];
  __shared__ __align__(16) char Blds[16384];

  const int bt = blockIdx.x;
  const int nr = ws[WS_TNR + bt];
  if (nr == 0) return;
  const int e  = ws[WS_TE + bt];
  const int rs = ws[WS_TRS + bt];
  const int r  = blockIdx.y;
  const int h0 = blockIdx.z * BN;
  const int* __restrict__ ridx = ws + WS_RIDX;

  const int tid = threadIdx.x;
  const int wv  = tid >> 6;
  const int ln  = tid & 63;
  const int g   = ln >> 4;
  const int c16 = ln & 15;
  const int wr = wv >> 1, wc = wv & 1;

  size_t   asrc[4];
  uint32_t awr[4];
#pragma unroll
  for (int i = 0; i < 4; ++i) {
    int q   = (tid + i * 256) * 16;
    int row = q >> 7;
    int el0 = (q & 127) >> 1;
    int rcl = row < nr ? row : nr - 1;
    int slot = ridx[rs + rcl];
    asrc[i] = (size_t)slot * Kp_ + el0;
    awr[i]  = row * 128 + ((q & 127) ^ ((row & 7) << 4));
  }
  const int p  = tid & 63;
  const int kh = tid >> 6;
  const int hr0 = 2 * p, hr1 = 2 * p + 1;
  uint32_t bw[4];
#pragma unroll
  for (int q = 0; q < 2; ++q) {
    bw[q]     = hr0 * 128 + ((kh * 32 + q * 16) ^ ((hr0 & 7) << 4));
    bw[2 + q] = hr1 * 128 + ((kh * 32 + q * 16) ^ ((hr1 & 7) << 4));
  }
  uint32_t aoff[4][2], boff[4][2];
#pragma unroll
  for (int mi = 0; mi < 4; ++mi) {
    int row = wr * 64 + mi * 16 + c16;
#pragma unroll
    for (int ks = 0; ks < 2; ++ks)
      aoff[mi][ks] = row * 128 + ((ks * 64 + g * 16) ^ ((row & 7) << 4));
  }
#pragma unroll
  for (int ni = 0; ni < 4; ++ni) {
    int row = wc * 64 + ni * 16 + c16;
#pragma unroll
    for (int ks = 0; ks < 2; ++ks)
      boff[ni][ks] = row * 128 + ((ks * 64 + g * 16) ^ ((row & 7) << 4));
  }

  f32x4 acc[4][4];
#pragma unroll
  for (int mi = 0; mi < 4; ++mi)
#pragma unroll
    for (int ni = 0; ni < 4; ++ni)
      acc[mi][ni] = f32x4{0.f, 0.f, 0.f, 0.f};

  const float* xbase = x + (size_t)r * MT_ * Kp_;
  const float* wbase = w + ((size_t)(r * E_ + e) * Kp_) * (size_t)H_ + h0;

  for (int kk = 0; kk < Kp_ / BK; ++kk) {
    const float* xk = xbase + (kk << 6);
    const float* wk = wbase + (size_t)(kk << 6) * H_;
    f32x4 av0[4], av1[4];
    f32x2 bv[16];
#pragma unroll
    for (int i = 0; i < 4; ++i) {
      av0[i] = *(const f32x4*)(xk + asrc[i]);
      av1[i] = *(const f32x4*)(xk + asrc[i] + 4);
    }
#pragma unroll
    for (int i = 0; i < 16; ++i)
      bv[i] = *(const f32x2*)(wk + (size_t)(kh * 16 + i) * H_ + 2 * p);
    __syncthreads();
#pragma unroll
    for (int i = 0; i < 4; ++i) {
      union { f16x8 v; h16x2 h[4]; } u;
      u.h[0] = __builtin_amdgcn_cvt_pkrtz(av0[i][0], av0[i][1]);
      u.h[1] = __builtin_amdgcn_cvt_pkrtz(av0[i][2], av0[i][3]);
      u.h[2] = __builtin_amdgcn_cvt_pkrtz(av1[i][0], av1[i][1]);
      u.h[3] = __builtin_amdgcn_cvt_pkrtz(av1[i][2], av1[i][3]);
      *(f16x8*)(Alds + awr[i]) = u.v;
    }
#pragma unroll
    for (int q = 0; q < 2; ++q) {
      union { f16x8 v; h16x2 h[4]; } lo, hi;
#pragma unroll
      for (int j = 0; j < 4; ++j) {
        lo.h[j] = __builtin_amdgcn_cvt_pkrtz(bv[q * 8 + 2 * j][0], bv[q * 8 + 2 * j + 1][0]);
        hi.h[j] = __builtin_amdgcn_cvt_pkrtz(bv[q * 8 + 2 * j][1], bv[q * 8 + 2 * j + 1][1]);
      }
      *(f16x8*)(Blds + bw[q])     = lo.v;
      *(f16x8*)(Blds + bw[2 + q]) = hi.v;
    }
    __syncthreads();
#pragma unroll
    for (int ks = 0; ks < 2; ++ks) {
      f16x8 af[4], bf[4];
#pragma unroll
      for (int mi = 0; mi < 4; ++mi)
        af[mi] = *(const f16x8*)(Alds + aoff[mi][ks]);
#pragma unroll
      for (int ni = 0; ni < 4; ++ni)
        bf[ni] = *(const f16x8*)(Blds + boff[ni][ks]);
#pragma unroll
      for (int mi = 0; mi < 4; ++mi)
#pragma unroll
        for (int ni = 0; ni < 4; ++ni)
          acc[mi][ni] = __builtin_amdgcn_mfma_f32_16x16x32_f16(
              af[mi], bf[ni], acc[mi][ni], 0, 0, 0);
    }
  }

#pragma unroll
  for (int mi = 0; mi < 4; ++mi) {
#pragma unroll
    for (int jj = 0; jj < 4; ++jj) {
      int row = wr * 64 + mi * 16 + g * 4 + jj;
      if (row < nr) {
        int m   = ridx[rs + row];
        float twv = tw[m];
        int t = m >> 1;
        float* op = out + (size_t)t * H_ + h0 + wc * 64 + c16;
#pragma unroll
        for (int ni = 0; ni < 4; ++ni)
          atomicAdd(op + ni * 16, acc[mi][ni][jj] * twv);
      }
    }
  }
}

// ---------------------------------------------------------------------------
extern "C" void kernel_launch(void* const* d_in, const int* in_sizes, int n_in,
                              void* d_out, int out_size, void* d_ws, size_t ws_size,
                              hipStream_t stream) {
  const float* x   = (const float*)d_in[0];   // [R, MT, Kp]   fp32
  const float* w   = (const float*)d_in[1];   // [R, E, Kp, H] fp32
  const int*   ids = (const int*)d_in[2];     // [T, TOPK] int32
  const float* tw  = (const float*)d_in[3];   // [T, TOPK] fp32
  float* out = (float*)d_out;                 // [T, H] fp32
  int* ws = (int*)d_ws;

  (void)hipMemsetAsync(d_out, 0, (size_t)T_ * H_ * 4, stream);
  hipLaunchKernelGGL(moe_prep, dim3(1), dim3(256), 0, stream, ids, ws);

  if (ws_size >= WS_NEEDED) {
    _Float16* x16  = (_Float16*)((char*)d_ws + WS_X16_OFF);
    _Float16* w16t = (_Float16*)((char*)d_ws + WS_W16T_OFF);
    hipLaunchKernelGGL(cvt_x, dim3(2048), dim3(256), 0, stream, x, x16);
    hipLaunchKernelGGL(transpose_w, dim3(Kp_ / 64, H_ / 64, R_ * E_),
                       dim3(256), 0, stream, w, w16t);
    hipLaunchKernelGGL(moe_gemm16, dim3(MAXT, H_ / BN), dim3(256), 0, stream,
                       x16, w16t, tw, ws, out);
  } else {
    hipLaunchKernelGGL(moe_gemm_fb, dim3(MAXT, R_, H_ / BN), dim3(256), 0,
                       stream, x, w, tw, ws, out);
  }
}

// Round 14
// 478.783 us; speedup vs baseline: 1.3828x; 1.0521x over previous
//
#include <hip/hip_runtime.h>
#include <stdint.h>

// ---------------- problem constants (fixed by setup_inputs) ----------------
#define R_    4
#define T_    2048
#define TOPK_ 2
#define MT_   (T_ * TOPK_)   // 4096
#define Kp_   1024
#define E_    8
#define H_    4096

// ---------------- tiling ----------------
#define BM 128
#define BN 128
#define BK 64
#define NKI 64                  // total K-steps (R_*Kp_/BK)
#define MAXT 40                 // >= sum ceil(cnt_e/128)

// ws layout: tables | x16 | w16T
#define WS_TE    16
#define WS_TRS   80
#define WS_TNR   144
#define WS_RIDX  256
#define WS_X16_OFF   32768
#define WS_X16_BYTES ((size_t)R_ * MT_ * Kp_ * 2)          // 33.5 MB
#define WS_W16T_OFF  (WS_X16_OFF + WS_X16_BYTES)
#define WS_W16T_BYTES ((size_t)R_ * E_ * H_ * Kp_ * 2)     // 268.4 MB
#define WS_NEEDED    (WS_W16T_OFF + WS_W16T_BYTES)

typedef _Float16 f16x8 __attribute__((ext_vector_type(8)));
typedef __fp16   h16x2 __attribute__((ext_vector_type(2)));   // cvt_pkrtz ret
typedef float    f32x4 __attribute__((ext_vector_type(4)));
typedef float    f32x2 __attribute__((ext_vector_type(2)));

__device__ __forceinline__ void gload_lds16(const void* g, void* l) {
  __builtin_amdgcn_global_load_lds(
      (const __attribute__((address_space(1))) uint8_t*)g,
      (__attribute__((address_space(3))) uint8_t*)l, 16, 0, 0);
}

// ---------------------------------------------------------------------------
// Kernel A: bin slots by expert in ws (placement-invariant row order)
// ---------------------------------------------------------------------------
__global__ void moe_prep(const int* __restrict__ ids, int* __restrict__ ws) {
  __shared__ int cnt[E_], off[E_], cur[E_];
  const int tid = threadIdx.x;
  if (tid < E_) { cnt[tid] = 0; cur[tid] = 0; }
  __syncthreads();
  for (int m = tid; m < MT_; m += 256) atomicAdd(&cnt[ids[m]], 1);
  __syncthreads();
  if (tid == 0) {
    int o = 0, nt = 0;
    for (int e = 0; e < E_; ++e) {
      off[e] = o;
      int c = cnt[e];
      for (int t = 0; t < (c + BM - 1) / BM; ++t) {
        ws[WS_TE + nt]  = e;
        ws[WS_TRS + nt] = o + t * BM;
        int rem = c - t * BM;
        ws[WS_TNR + nt] = rem < BM ? rem : BM;
        ++nt;
      }
      o += c;
    }
    for (; nt < MAXT; ++nt) ws[WS_TNR + nt] = 0;
  }
  __syncthreads();
  for (int m = tid; m < MT_; m += 256) {
    int e = ids[m];
    int p = off[e] + atomicAdd(&cur[e], 1);
    ws[WS_RIDX + p] = m;
  }
}

// ---------------------------------------------------------------------------
// Kernel B1: x fp32 -> fp16 (exact; values are fp16-representable)
// ---------------------------------------------------------------------------
__global__ void cvt_x(const float* __restrict__ x, _Float16* __restrict__ x16) {
  const size_t n = (size_t)R_ * MT_ * Kp_;
  size_t i = ((size_t)blockIdx.x * 256 + threadIdx.x) * 8;
  const size_t stride = (size_t)gridDim.x * 256 * 8;
  for (; i < n; i += stride) {
    f32x4 a = *(const f32x4*)(x + i);
    f32x4 b = *(const f32x4*)(x + i + 4);
    union { f16x8 v; h16x2 h[4]; } u;
    u.h[0] = __builtin_amdgcn_cvt_pkrtz(a[0], a[1]);
    u.h[1] = __builtin_amdgcn_cvt_pkrtz(a[2], a[3]);
    u.h[2] = __builtin_amdgcn_cvt_pkrtz(b[0], b[1]);
    u.h[3] = __builtin_amdgcn_cvt_pkrtz(b[2], b[3]);
    *(f16x8*)(x16 + i) = u.v;
  }
}

// ---------------------------------------------------------------------------
// Kernel B2: w [r][e][k][h] fp32 -> w16T [r][e][h][k] fp16, 64x64 LDS tiles
// ---------------------------------------------------------------------------
__global__ __launch_bounds__(256) void transpose_w(
    const float* __restrict__ w, _Float16* __restrict__ w16t) {
  __shared__ _Float16 tl[64][72];
  const int k0 = blockIdx.x * 64, h0 = blockIdx.y * 64;
  const float* wp = w + (size_t)blockIdx.z * Kp_ * H_;
  _Float16*    op = w16t + (size_t)blockIdx.z * H_ * Kp_;
  const int t4 = threadIdx.x & 15, kq = threadIdx.x >> 4;
#pragma unroll
  for (int i = 0; i < 4; ++i) {
    int k = k0 + kq * 4 + i;
    f32x4 v = *(const f32x4*)(wp + (size_t)k * H_ + h0 + t4 * 4);
#pragma unroll
    for (int j = 0; j < 4; ++j) tl[t4 * 4 + j][kq * 4 + i] = (_Float16)v[j];
  }
  __syncthreads();
  const int row = threadIdx.x >> 2, seg = threadIdx.x & 3;
  f16x8 o0, o1;
#pragma unroll
  for (int j = 0; j < 8; ++j) { o0[j] = tl[row][seg * 16 + j]; o1[j] = tl[row][seg * 16 + 8 + j]; }
  _Float16* dst = op + (size_t)(h0 + row) * Kp_ + k0 + seg * 16;
  *(f16x8*)dst = o0;
  *(f16x8*)(dst + 8) = o1;
}

// ---------------------------------------------------------------------------
// Kernel C: grouped GEMM on fp16 ws tensors. 128x128xBK64, full K=4096/block.
// T3/T4-minimum pipeline: double-buffered LDS, STAGE(k+1) issued at top of
// iter k, counted s_waitcnt vmcnt(8) (never 0 in loop), raw s_barrier (no
// __syncthreads: it would re-insert the vmcnt(0) drain), sched_barrier pins.
// Both operands staged with global_load_lds width-16 (linear LDS dest,
// inverse-XOR-swizzled source), fragments via swizzled ds_read_b128.
// ---------------------------------------------------------------------------
__global__ __launch_bounds__(256) void moe_gemm16(
    const _Float16* __restrict__ x16, const _Float16* __restrict__ w16t,
    const float* __restrict__ tw, const int* __restrict__ ws,
    float* __restrict__ out)
{
  __shared__ __align__(16) char Alds[2][16384];
  __shared__ __align__(16) char Blds[2][16384];

  const int bt = blockIdx.x;
  const int nr = ws[WS_TNR + bt];
  if (nr == 0) return;
  const int e  = ws[WS_TE + bt];
  const int rs = ws[WS_TRS + bt];
  const int h0 = blockIdx.y * BN;
  const int* __restrict__ ridx = ws + WS_RIDX;

  const int tid = threadIdx.x;
  const int wv  = tid >> 6;
  const int ln  = tid & 63;
  const int g   = ln >> 4;
  const int c16 = ln & 15;
  const int wr = wv >> 1, wc = wv & 1;

  // staging source offsets (K-invariant): chunk covers LDS byte q
  size_t asrc[4], bsrc[4];
#pragma unroll
  for (int i = 0; i < 4; ++i) {
    int q   = (tid + i * 256) * 16;
    int row = q >> 7;
    int col = (q & 127) ^ (((q >> 7) & 7) << 4);   // inverse swizzle
    int rcl = row < nr ? row : nr - 1;
    int slot = ridx[rs + rcl];
    asrc[i] = (size_t)slot * (Kp_ * 2) + col;
    bsrc[i] = (size_t)(h0 + row) * (Kp_ * 2) + col;
  }

  // fragment read offsets (proven in rounds 10/13)
  uint32_t aoff[4][2], boff[4][2];
#pragma unroll
  for (int mi = 0; mi < 4; ++mi) {
    int row = wr * 64 + mi * 16 + c16;
#pragma unroll
    for (int ks = 0; ks < 2; ++ks)
      aoff[mi][ks] = row * 128 + ((ks * 64 + g * 16) ^ ((row & 7) << 4));
  }
#pragma unroll
  for (int ni = 0; ni < 4; ++ni) {
    int row = wc * 64 + ni * 16 + c16;
#pragma unroll
    for (int ks = 0; ks < 2; ++ks)
      boff[ni][ks] = row * 128 + ((ks * 64 + g * 16) ^ ((row & 7) << 4));
  }

  f32x4 acc[4][4];
#pragma unroll
  for (int mi = 0; mi < 4; ++mi)
#pragma unroll
    for (int ni = 0; ni < 4; ++ni)
      acc[mi][ni] = f32x4{0.f, 0.f, 0.f, 0.f};

  const char* xb = (const char*)x16;
  const char* wb = (const char*)w16t + (size_t)e * H_ * Kp_ * 2;

#define STAGE(BUF_, KK_) do {                                               \
    const int r_ = (KK_) >> 4, kp_ = ((KK_) & 15) << 6;                     \
    const char* xk_ = xb + ((size_t)r_ * MT_ * Kp_ + kp_) * 2;              \
    const char* wk_ = wb + ((size_t)r_ * E_ * H_ * Kp_ + kp_) * 2;          \
    _Pragma("unroll")                                                       \
    for (int i_ = 0; i_ < 4; ++i_)                                          \
      gload_lds16(xk_ + asrc[i_], Alds[BUF_] + i_ * 4096 + wv * 1024);      \
    _Pragma("unroll")                                                       \
    for (int i_ = 0; i_ < 4; ++i_)                                          \
      gload_lds16(wk_ + bsrc[i_], Blds[BUF_] + i_ * 4096 + wv * 1024);      \
  } while (0)

#define COMPUTE(BUF_) do {                                                  \
    _Pragma("unroll")                                                       \
    for (int ks = 0; ks < 2; ++ks) {                                        \
      f16x8 af[4], bf[4];                                                   \
      _Pragma("unroll")                                                     \
      for (int mi = 0; mi < 4; ++mi)                                        \
        af[mi] = *(const f16x8*)(Alds[BUF_] + aoff[mi][ks]);                \
      _Pragma("unroll")                                                     \
      for (int ni = 0; ni < 4; ++ni)                                        \
        bf[ni] = *(const f16x8*)(Blds[BUF_] + boff[ni][ks]);                \
      __builtin_amdgcn_s_setprio(1);                                        \
      _Pragma("unroll")                                                     \
      for (int mi = 0; mi < 4; ++mi)                                        \
        _Pragma("unroll")                                                   \
        for (int ni = 0; ni < 4; ++ni)                                      \
          acc[mi][ni] = __builtin_amdgcn_mfma_f32_16x16x32_f16(             \
              af[mi], bf[ni], acc[mi][ni], 0, 0, 0);                        \
      __builtin_amdgcn_s_setprio(0);                                        \
    }                                                                       \
  } while (0)

  STAGE(0, 0);                                   // prologue: tile 0 -> buf 0
  for (int kk = 0; kk < NKI - 1; ++kk) {
    const int cur = kk & 1;
    STAGE(cur ^ 1, kk + 1);                      // issue next tile, no wait
    asm volatile("s_waitcnt vmcnt(8)" ::: "memory");  // tile kk landed
    __builtin_amdgcn_s_barrier();
    __builtin_amdgcn_sched_barrier(0);
    COMPUTE(cur);
    __builtin_amdgcn_sched_barrier(0);           // pin reads before barrier
    __builtin_amdgcn_s_barrier();                // WAR: all done reading cur
  }
  asm volatile("s_waitcnt vmcnt(0)" ::: "memory");
  __builtin_amdgcn_s_barrier();
  __builtin_amdgcn_sched_barrier(0);
  COMPUTE((NKI - 1) & 1);                        // tile 63 from buf 1

#undef STAGE
#undef COMPUTE

  // epilogue: tw-scale + atomic combine (<=2 writers per element)
#pragma unroll
  for (int mi = 0; mi < 4; ++mi) {
#pragma unroll
    for (int jj = 0; jj < 4; ++jj) {
      int row = wr * 64 + mi * 16 + g * 4 + jj;
      if (row < nr) {
        int m   = ridx[rs + row];
        float twv = tw[m];
        int t = m >> 1;
        float* op = out + (size_t)t * H_ + h0 + wc * 64 + c16;
#pragma unroll
        for (int ni = 0; ni < 4; ++ni)
          atomicAdd(op + ni * 16, acc[mi][ni][jj] * twv);
      }
    }
  }
}

// ---------------------------------------------------------------------------
// Fallback GEMM (round-12 PASS path): fp32 ingestion, reg-stage + cvt_pkrtz
// ---------------------------------------------------------------------------
__global__ __launch_bounds__(256) void moe_gemm_fb(
    const float* __restrict__ x, const float* __restrict__ w,
    const float* __restrict__ tw, const int* __restrict__ ws,
    float* __restrict__ out)
{
  __shared__ __align__(16) char Alds[16384];
  __shared__ __align__(16) char Blds[16384];

  const int bt = blockIdx.x;
  const int nr = ws[WS_TNR + bt];
  if (nr == 0) return;
  const int e  = ws[WS_TE + bt];
  const int rs = ws[WS_TRS + bt];
  const int r  = blockIdx.y;
  const int h0 = blockIdx.z * BN;
  const int* __restrict__ ridx = ws + WS_RIDX;

  const int tid = threadIdx.x;
  const int wv  = tid >> 6;
  const int ln  = tid & 63;
  const int g   = ln >> 4;
  const int c16 = ln & 15;
  const int wr = wv >> 1, wc = wv & 1;

  size_t   asrc[4];
  uint32_t awr[4];
#pragma unroll
  for (int i = 0; i < 4; ++i) {
    int q   = (tid + i * 256) * 16;
    int row = q >> 7;
    int el0 = (q & 127) >> 1;
    int rcl = row < nr ? row : nr - 1;
    int slot = ridx[rs + rcl];
    asrc[i] = (size_t)slot * Kp_ + el0;
    awr[i]  = row * 128 + ((q & 127) ^ ((row & 7) << 4));
  }
  const int p  = tid & 63;
  const int kh = tid >> 6;
  const int hr0 = 2 * p, hr1 = 2 * p + 1;
  uint32_t bw[4];
#pragma unroll
  for (int q = 0; q < 2; ++q) {
    bw[q]     = hr0 * 128 + ((kh * 32 + q * 16) ^ ((hr0 & 7) << 4));
    bw[2 + q] = hr1 * 128 + ((kh * 32 + q * 16) ^ ((hr1 & 7) << 4));
  }
  uint32_t aoff[4][2], boff[4][2];
#pragma unroll
  for (int mi = 0; mi < 4; ++mi) {
    int row = wr * 64 + mi * 16 + c16;
#pragma unroll
    for (int ks = 0; ks < 2; ++ks)
      aoff[mi][ks] = row * 128 + ((ks * 64 + g * 16) ^ ((row & 7) << 4));
  }
#pragma unroll
  for (int ni = 0; ni < 4; ++ni) {
    int row = wc * 64 + ni * 16 + c16;
#pragma unroll
    for (int ks = 0; ks < 2; ++ks)
      boff[ni][ks] = row * 128 + ((ks * 64 + g * 16) ^ ((row & 7) << 4));
  }

  f32x4 acc[4][4];
#pragma unroll
  for (int mi = 0; mi < 4; ++mi)
#pragma unroll
    for (int ni = 0; ni < 4; ++ni)
      acc[mi][ni] = f32x4{0.f, 0.f, 0.f, 0.f};

  const float* xbase = x + (size_t)r * MT_ * Kp_;
  const float* wbase = w + ((size_t)(r * E_ + e) * Kp_) * (size_t)H_ + h0;

  for (int kk = 0; kk < Kp_ / BK; ++kk) {
    const float* xk = xbase + (kk << 6);
    const float* wk = wbase + (size_t)(kk << 6) * H_;
    f32x4 av0[4], av1[4];
    f32x2 bv[16];
#pragma unroll
    for (int i = 0; i < 4; ++i) {
      av0[i] = *(const f32x4*)(xk + asrc[i]);
      av1[i] = *(const f32x4*)(xk + asrc[i] + 4);
    }
#pragma unroll
    for (int i = 0; i < 16; ++i)
      bv[i] = *(const f32x2*)(wk + (size_t)(kh * 16 + i) * H_ + 2 * p);
    __syncthreads();
#pragma unroll
    for (int i = 0; i < 4; ++i) {
      union { f16x8 v; h16x2 h[4]; } u;
      u.h[0] = __builtin_amdgcn_cvt_pkrtz(av0[i][0], av0[i][1]);
      u.h[1] = __builtin_amdgcn_cvt_pkrtz(av0[i][2], av0[i][3]);
      u.h[2] = __builtin_amdgcn_cvt_pkrtz(av1[i][0], av1[i][1]);
      u.h[3] = __builtin_amdgcn_cvt_pkrtz(av1[i][2], av1[i][3]);
      *(f16x8*)(Alds + awr[i]) = u.v;
    }
#pragma unroll
    for (int q = 0; q < 2; ++q) {
      union { f16x8 v; h16x2 h[4]; } lo, hi;
#pragma unroll
      for (int j = 0; j < 4; ++j) {
        lo.h[j] = __builtin_amdgcn_cvt_pkrtz(bv[q * 8 + 2 * j][0], bv[q * 8 + 2 * j + 1][0]);
        hi.h[j] = __builtin_amdgcn_cvt_pkrtz(bv[q * 8 + 2 * j][1], bv[q * 8 + 2 * j + 1][1]);
      }
      *(f16x8*)(Blds + bw[q])     = lo.v;
      *(f16x8*)(Blds + bw[2 + q]) = hi.v;
    }
    __syncthreads();
#pragma unroll
    for (int ks = 0; ks < 2; ++ks) {
      f16x8 af[4], bf[4];
#pragma unroll
      for (int mi = 0; mi < 4; ++mi)
        af[mi] = *(const f16x8*)(Alds + aoff[mi][ks]);
#pragma unroll
      for (int ni = 0; ni < 4; ++ni)
        bf[ni] = *(const f16x8*)(Blds + boff[ni][ks]);
#pragma unroll
      for (int mi = 0; mi < 4; ++mi)
#pragma unroll
        for (int ni = 0; ni < 4; ++ni)
          acc[mi][ni] = __builtin_amdgcn_mfma_f32_16x16x32_f16(
              af[mi], bf[ni], acc[mi][ni], 0, 0, 0);
    }
  }

#pragma unroll
  for (int mi = 0; mi < 4; ++mi) {
#pragma unroll
    for (int jj = 0; jj < 4; ++jj) {
      int row = wr * 64 + mi * 16 + g * 4 + jj;
      if (row < nr) {
        int m   = ridx[rs + row];
        float twv = tw[m];
        int t = m >> 1;
        float* op = out + (size_t)t * H_ + h0 + wc * 64 + c16;
#pragma unroll
        for (int ni = 0; ni < 4; ++ni)
          atomicAdd(op + ni * 16, acc[mi][ni][jj] * twv);
      }
    }
  }
}

// ---------------------------------------------------------------------------
extern "C" void kernel_launch(void* const* d_in, const int* in_sizes, int n_in,
                              void* d_out, int out_size, void* d_ws, size_t ws_size,
                              hipStream_t stream) {
  const float* x   = (const float*)d_in[0];   // [R, MT, Kp]   fp32
  const float* w   = (const float*)d_in[1];   // [R, E, Kp, H] fp32
  const int*   ids = (const int*)d_in[2];     // [T, TOPK] int32
  const float* tw  = (const float*)d_in[3];   // [T, TOPK] fp32
  float* out = (float*)d_out;                 // [T, H] fp32
  int* ws = (int*)d_ws;

  (void)hipMemsetAsync(d_out, 0, (size_t)T_ * H_ * 4, stream);
  hipLaunchKernelGGL(moe_prep, dim3(1), dim3(256), 0, stream, ids, ws);

  if (ws_size >= WS_NEEDED) {
    _Float16* x16  = (_Float16*)((char*)d_ws + WS_X16_OFF);
    _Float16* w16t = (_Float16*)((char*)d_ws + WS_W16T_OFF);
    hipLaunchKernelGGL(cvt_x, dim3(2048), dim3(256), 0, stream, x, x16);
    hipLaunchKernelGGL(transpose_w, dim3(Kp_ / 64, H_ / 64, R_ * E_),
                       dim3(256), 0, stream, w, w16t);
    hipLaunchKernelGGL(moe_gemm16, dim3(MAXT, H_ / BN), dim3(256), 0, stream,
                       x16, w16t, tw, ws, out);
  } else {
    hipLaunchKernelGGL(moe_gemm_fb, dim3(MAXT, R_, H_ / BN), dim3(256), 0,
                       stream, x, w, tw, ws, out);
  }
}